// Round 1
// baseline (1451.263 us; speedup 1.0000x reference)
//
#include <hip/hip_runtime.h>
#include <hip/hip_bf16.h>
#include <stdint.h>

#define IN_F   4096
#define OUT_F  11008
#define NG     32

typedef __bf16 bf16_t;
typedef __bf16 bf16x8 __attribute__((ext_vector_type(8)));
typedef float  f32x4  __attribute__((ext_vector_type(4)));

// ---------------- kernel 1: xs[m,k] = bf16(x[m,k] * input_scale[k]) ----------------
__global__ __launch_bounds__(256) void scale_cast_kernel(
    const float* __restrict__ x, const float* __restrict__ iscale,
    bf16_t* __restrict__ xs)
{
    size_t idx = ((size_t)blockIdx.x * 256 + threadIdx.x) * 8;
    const float4 a0 = *(const float4*)(x + idx);
    const float4 a1 = *(const float4*)(x + idx + 4);
    const int k = (int)(idx & (IN_F - 1));       // IN_F is power of two
    const float4 s0 = *(const float4*)(iscale + k);
    const float4 s1 = *(const float4*)(iscale + k + 4);
    bf16x8 o;
    o[0] = (bf16_t)(a0.x * s0.x);
    o[1] = (bf16_t)(a0.y * s0.y);
    o[2] = (bf16_t)(a0.z * s0.z);
    o[3] = (bf16_t)(a0.w * s0.w);
    o[4] = (bf16_t)(a1.x * s1.x);
    o[5] = (bf16_t)(a1.y * s1.y);
    o[6] = (bf16_t)(a1.z * s1.z);
    o[7] = (bf16_t)(a1.w * s1.w);
    *(bf16x8*)(xs + idx) = o;
}

// ---------------- kernel 2: W[n,k] = bf16((q - zero[n,g]) * scale[n,g]) ------------
// qweight[n][j] holds one byte (two nibbles, HIGH nibble first -> k=2j, low -> k=2j+1)
__global__ __launch_bounds__(256) void dequant_kernel(
    const int* __restrict__ qw, const float* __restrict__ scales,
    const float* __restrict__ zeros, bf16_t* __restrict__ wq)
{
    const size_t tid = (size_t)blockIdx.x * 256 + threadIdx.x;
    const int4 q = *(const int4*)(qw + tid * 4);
    const size_t jj = tid * 4;                 // byte index (linear over [n][j])
    const int n = (int)(jj >> 11);             // /2048 bytes per row
    const int j = (int)(jj & 2047);
    const int g = j >> 6;                      // group of k=2j: (2j)/128 = j/64
    const float s = scales[n * NG + g];
    const float z = zeros[n * NG + g];
    bf16x8 o;
    o[0] = (bf16_t)(((float)((q.x >> 4) & 15) - z) * s);
    o[1] = (bf16_t)(((float)( q.x       & 15) - z) * s);
    o[2] = (bf16_t)(((float)((q.y >> 4) & 15) - z) * s);
    o[3] = (bf16_t)(((float)( q.y       & 15) - z) * s);
    o[4] = (bf16_t)(((float)((q.z >> 4) & 15) - z) * s);
    o[5] = (bf16_t)(((float)( q.z       & 15) - z) * s);
    o[6] = (bf16_t)(((float)((q.w >> 4) & 15) - z) * s);
    o[7] = (bf16_t)(((float)( q.w       & 15) - z) * s);
    *(bf16x8*)(wq + (size_t)n * IN_F + 2 * j) = o;
}

// ---------------- kernel 3: C[M,N] = A[M,K] * B[N,K]^T + bias ----------------------
// m97-structure: 128x128 tile, BK=32, 4 waves, each wave 64x64 via 4x4 of 16x16x32
#define BM 128
#define BN 128
#define BK 32

__global__ __launch_bounds__(256) void gemm_bt_kernel(
    const bf16_t* __restrict__ A,   // [M, IN_F]
    const bf16_t* __restrict__ B,   // [OUT_F, IN_F]
    const float* __restrict__ bias, // [OUT_F]
    float* __restrict__ C)          // [M, OUT_F]
{
    constexpr int K = IN_F;
    constexpr int N = OUT_F;
    __shared__ bf16_t As[BM * BK];  // 8 KB, row-major [row][32], no padding (global_load_lds)
    __shared__ bf16_t Bs[BN * BK];  // 8 KB

    const int t    = threadIdx.x;
    const int lane = t & 63;
    const int wave = t >> 6;
    const int wm = (wave >> 1) * 64;   // wave's 64x64 quadrant
    const int wn = (wave & 1) * 64;
    const int m0 = blockIdx.y * BM;
    const int n0 = blockIdx.x * BN;

    // Staging: tile is 128 rows x 64 B. Chunk c = r*256 + t covers row c>>2, 16B piece c&3.
    const int srow  = t >> 2;          // 0..63 (round adds +64)
    const int selem = (t & 3) * 8;     // element offset within row (8 bf16 = 16 B)

    const bf16_t* agp0 = A + (size_t)(m0 + srow) * K + selem;
    const bf16_t* agp1 = A + (size_t)(m0 + 64 + srow) * K + selem;
    const bf16_t* bgp0 = B + (size_t)(n0 + srow) * K + selem;
    const bf16_t* bgp1 = B + (size_t)(n0 + 64 + srow) * K + selem;

    // LDS destinations: HW uses readfirstlane(base) + lane*16; lane0 value = wave base.
    bf16_t* al0 = As + (size_t)t * 8;
    bf16_t* al1 = As + (size_t)(256 + t) * 8;
    bf16_t* bl0 = Bs + (size_t)t * 8;
    bf16_t* bl1 = Bs + (size_t)(256 + t) * 8;

    const int fm = lane & 15;          // A/B fragment: row = lane&15
    const int fk = (lane >> 4) * 8;    // k-offset = quad*8

    f32x4 acc[4][4] = {};

    for (int kt = 0; kt < K; kt += BK) {
        __builtin_amdgcn_global_load_lds(
            (const __attribute__((address_space(1))) void*)(agp0 + kt),
            (__attribute__((address_space(3))) void*)al0, 16, 0, 0);
        __builtin_amdgcn_global_load_lds(
            (const __attribute__((address_space(1))) void*)(agp1 + kt),
            (__attribute__((address_space(3))) void*)al1, 16, 0, 0);
        __builtin_amdgcn_global_load_lds(
            (const __attribute__((address_space(1))) void*)(bgp0 + kt),
            (__attribute__((address_space(3))) void*)bl0, 16, 0, 0);
        __builtin_amdgcn_global_load_lds(
            (const __attribute__((address_space(1))) void*)(bgp1 + kt),
            (__attribute__((address_space(3))) void*)bl1, 16, 0, 0);
        __syncthreads();   // compiler emits s_waitcnt vmcnt(0) before s_barrier

        bf16x8 af[4], bfr[4];
        #pragma unroll
        for (int i = 0; i < 4; ++i)
            af[i] = *(const bf16x8*)(As + (wm + i * 16 + fm) * BK + fk);
        #pragma unroll
        for (int j = 0; j < 4; ++j)
            bfr[j] = *(const bf16x8*)(Bs + (wn + j * 16 + fm) * BK + fk);

        #pragma unroll
        for (int i = 0; i < 4; ++i)
            #pragma unroll
            for (int j = 0; j < 4; ++j)
                acc[i][j] = __builtin_amdgcn_mfma_f32_16x16x32_bf16(
                    af[i], bfr[j], acc[i][j], 0, 0, 0);
        __syncthreads();   // protect LDS before next stage
    }

    // Epilogue: C/D layout col=lane&15, row=(lane>>4)*4+reg  (m89/m91-verified)
    const int cn = lane & 15;
    const int cm = (lane >> 4) * 4;
    #pragma unroll
    for (int j = 0; j < 4; ++j) {
        const int col = n0 + wn + j * 16 + cn;
        const float bj = bias[col];
        #pragma unroll
        for (int i = 0; i < 4; ++i) {
            const int row = m0 + wm + i * 16 + cm;
            float* cp = C + (size_t)row * N + col;
            #pragma unroll
            for (int r = 0; r < 4; ++r)
                cp[(size_t)r * N] = acc[i][j][r] + bj;
        }
    }
}

// ---------------- launch ----------------
extern "C" void kernel_launch(void* const* d_in, const int* in_sizes, int n_in,
                              void* d_out, int out_size, void* d_ws, size_t ws_size,
                              hipStream_t stream)
{
    const float* x      = (const float*)d_in[0];   // [4,2048,4096] f32
    const int*   qw     = (const int*)d_in[1];     // [11008,2048] i32 (byte vals)
    const float* scales = (const float*)d_in[2];   // [11008,32]
    const float* zeros  = (const float*)d_in[3];   // [11008,32]
    const float* iscale = (const float*)d_in[4];   // [4096]
    const float* bias   = (const float*)d_in[5];   // [11008]
    float* out = (float*)d_out;                    // [4,2048,11008] f32

    const int M = in_sizes[0] / IN_F;              // 8192

    // workspace layout: xs (M*IN_F bf16) | wq (OUT_F*IN_F bf16)  => ~157 MB
    bf16_t* xs = (bf16_t*)d_ws;
    bf16_t* wq = (bf16_t*)((char*)d_ws + (size_t)M * IN_F * sizeof(bf16_t));

    // 1) scale + cast x: 33.5M elems / 8 per thread
    scale_cast_kernel<<<(M * IN_F) / 2048, 256, 0, stream>>>(x, iscale, xs);
    // 2) dequant weights: 22.5M int32 / 4 per thread
    dequant_kernel<<<(OUT_F * (IN_F / 2)) / 1024, 256, 0, stream>>>(qw, scales, zeros, wq);
    // 3) GEMM + bias
    gemm_bt_kernel<<<dim3(OUT_F / BN, M / BM), 256, 0, stream>>>(xs, wq, bias, out);
}

// Round 2
// 1432.678 us; speedup vs baseline: 1.0130x; 1.0130x over previous
//
#include <hip/hip_runtime.h>
#include <hip/hip_bf16.h>
#include <stdint.h>

#define IN_F   4096
#define OUT_F  11008
#define NG     32

typedef __bf16 bf16_t;
typedef __bf16 bf16x8 __attribute__((ext_vector_type(8)));
typedef float  f32x4  __attribute__((ext_vector_type(4)));

// ---------------- kernel 1: xs[m,k] = bf16(x[m,k] * input_scale[k]) ----------------
__global__ __launch_bounds__(256) void scale_cast_kernel(
    const float* __restrict__ x, const float* __restrict__ iscale,
    bf16_t* __restrict__ xs)
{
    size_t idx = ((size_t)blockIdx.x * 256 + threadIdx.x) * 8;
    const float4 a0 = *(const float4*)(x + idx);
    const float4 a1 = *(const float4*)(x + idx + 4);
    const int k = (int)(idx & (IN_F - 1));       // IN_F is power of two
    const float4 s0 = *(const float4*)(iscale + k);
    const float4 s1 = *(const float4*)(iscale + k + 4);
    bf16x8 o;
    o[0] = (bf16_t)(a0.x * s0.x);
    o[1] = (bf16_t)(a0.y * s0.y);
    o[2] = (bf16_t)(a0.z * s0.z);
    o[3] = (bf16_t)(a0.w * s0.w);
    o[4] = (bf16_t)(a1.x * s1.x);
    o[5] = (bf16_t)(a1.y * s1.y);
    o[6] = (bf16_t)(a1.z * s1.z);
    o[7] = (bf16_t)(a1.w * s1.w);
    *(bf16x8*)(xs + idx) = o;
}

// ---------------- kernel 2: W[n,k] = bf16((q - zero[n,g]) * scale[n,g]) ------------
// qweight[n][j] holds one byte (two nibbles, HIGH nibble first -> k=2j, low -> k=2j+1)
__global__ __launch_bounds__(256) void dequant_kernel(
    const int* __restrict__ qw, const float* __restrict__ scales,
    const float* __restrict__ zeros, bf16_t* __restrict__ wq)
{
    const size_t tid = (size_t)blockIdx.x * 256 + threadIdx.x;
    const int4 q = *(const int4*)(qw + tid * 4);
    const size_t jj = tid * 4;                 // byte index (linear over [n][j])
    const int n = (int)(jj >> 11);             // /2048 bytes per row
    const int j = (int)(jj & 2047);
    const int g = j >> 6;                      // group of k=2j: (2j)/128 = j/64
    const float s = scales[n * NG + g];
    const float z = zeros[n * NG + g];
    bf16x8 o;
    o[0] = (bf16_t)(((float)((q.x >> 4) & 15) - z) * s);
    o[1] = (bf16_t)(((float)( q.x       & 15) - z) * s);
    o[2] = (bf16_t)(((float)((q.y >> 4) & 15) - z) * s);
    o[3] = (bf16_t)(((float)( q.y       & 15) - z) * s);
    o[4] = (bf16_t)(((float)((q.z >> 4) & 15) - z) * s);
    o[5] = (bf16_t)(((float)( q.z       & 15) - z) * s);
    o[6] = (bf16_t)(((float)((q.w >> 4) & 15) - z) * s);
    o[7] = (bf16_t)(((float)( q.w       & 15) - z) * s);
    *(bf16x8*)(wq + (size_t)n * IN_F + 2 * j) = o;
}

// ---------------- kernel 3: C[M,N] = A[M,K] * B[N,K]^T + bias ----------------------
// m97-structure: 128x128 tile, BK=32, 4 waves, each wave 64x64 via 4x4 of 16x16x32.
// R2 change: LDS piece-swizzle. Row r (64 B = 4x16 B pieces) stores logical piece p
// at slot (p + (r>>1)) & 3. Applied on the GLOBAL-read side of global_load_lds
// (LDS dst is forced lane-linear). Kills the ~8-way bank conflict of the
// row*64B + quad*16B read pattern -> 2-way (free per m136).
#define BM 128
#define BN 128
#define BK 32

__global__ __launch_bounds__(256) void gemm_bt_kernel(
    const bf16_t* __restrict__ A,   // [M, IN_F]
    const bf16_t* __restrict__ B,   // [OUT_F, IN_F]
    const float* __restrict__ bias, // [OUT_F]
    float* __restrict__ C)          // [M, OUT_F]
{
    constexpr int K = IN_F;
    constexpr int N = OUT_F;
    __shared__ bf16_t As[BM * BK];  // 8 KB
    __shared__ bf16_t Bs[BN * BK];  // 8 KB

    const int t    = threadIdx.x;
    const int lane = t & 63;
    const int wave = t >> 6;
    const int wm = (wave >> 1) * 64;   // wave's 64x64 quadrant
    const int wn = (wave & 1) * 64;
    const int m0 = blockIdx.y * BM;
    const int n0 = blockIdx.x * BN;

    // Staging: thread t covers row t>>2 (local), LDS slot t&3.
    // Swizzle: slot s of row r holds logical piece p = (s - (r>>1)) & 3.
    const int srow  = t >> 2;                       // 0..63 (second segment adds +64; (64+r)>>1 preserves &3 term)
    const int piece = ((t & 3) - (t >> 3)) & 3;     // logical piece this lane must fetch
    const int selem = piece * 8;                    // element offset within row

    const bf16_t* agp0 = A + (size_t)(m0 + srow) * K + selem;
    const bf16_t* agp1 = A + (size_t)(m0 + 64 + srow) * K + selem;
    const bf16_t* bgp0 = B + (size_t)(n0 + srow) * K + selem;
    const bf16_t* bgp1 = B + (size_t)(n0 + 64 + srow) * K + selem;

    // LDS destinations: lane-linear (HW: wave-uniform base + lane*16)
    bf16_t* al0 = As + (size_t)t * 8;
    bf16_t* al1 = As + (size_t)(256 + t) * 8;
    bf16_t* bl0 = Bs + (size_t)t * 8;
    bf16_t* bl1 = Bs + (size_t)(256 + t) * 8;

    const int fm = lane & 15;          // fragment row within 16-block
    const int fq = lane >> 4;          // logical piece (quad) 0..3

    f32x4 acc[4][4] = {};

    for (int kt = 0; kt < K; kt += BK) {
        __builtin_amdgcn_global_load_lds(
            (const __attribute__((address_space(1))) void*)(agp0 + kt),
            (__attribute__((address_space(3))) void*)al0, 16, 0, 0);
        __builtin_amdgcn_global_load_lds(
            (const __attribute__((address_space(1))) void*)(agp1 + kt),
            (__attribute__((address_space(3))) void*)al1, 16, 0, 0);
        __builtin_amdgcn_global_load_lds(
            (const __attribute__((address_space(1))) void*)(bgp0 + kt),
            (__attribute__((address_space(3))) void*)bl0, 16, 0, 0);
        __builtin_amdgcn_global_load_lds(
            (const __attribute__((address_space(1))) void*)(bgp1 + kt),
            (__attribute__((address_space(3))) void*)bl1, 16, 0, 0);
        __syncthreads();

        bf16x8 af[4], bfr[4];
        #pragma unroll
        for (int i = 0; i < 4; ++i) {
            const int rl = wm + i * 16 + fm;                 // local row 0..127
            const int slot = (fq + (rl >> 1)) & 3;           // swizzled slot
            af[i] = *(const bf16x8*)(As + rl * BK + slot * 8);
        }
        #pragma unroll
        for (int j = 0; j < 4; ++j) {
            const int rl = wn + j * 16 + fm;
            const int slot = (fq + (rl >> 1)) & 3;
            bfr[j] = *(const bf16x8*)(Bs + rl * BK + slot * 8);
        }

        #pragma unroll
        for (int i = 0; i < 4; ++i)
            #pragma unroll
            for (int j = 0; j < 4; ++j)
                acc[i][j] = __builtin_amdgcn_mfma_f32_16x16x32_bf16(
                    af[i], bfr[j], acc[i][j], 0, 0, 0);
        __syncthreads();
    }

    // Epilogue: C/D layout col=lane&15, row=(lane>>4)*4+reg  (m89/m91-verified)
    const int cn = lane & 15;
    const int cm = (lane >> 4) * 4;
    #pragma unroll
    for (int j = 0; j < 4; ++j) {
        const int col = n0 + wn + j * 16 + cn;
        const float bj = bias[col];
        #pragma unroll
        for (int i = 0; i < 4; ++i) {
            const int row = m0 + wm + i * 16 + cm;
            float* cp = C + (size_t)row * N + col;
            #pragma unroll
            for (int r = 0; r < 4; ++r)
                cp[(size_t)r * N] = acc[i][j][r] + bj;
        }
    }
}

// ---------------- launch ----------------
extern "C" void kernel_launch(void* const* d_in, const int* in_sizes, int n_in,
                              void* d_out, int out_size, void* d_ws, size_t ws_size,
                              hipStream_t stream)
{
    const float* x      = (const float*)d_in[0];   // [4,2048,4096] f32
    const int*   qw     = (const int*)d_in[1];     // [11008,2048] i32 (byte vals)
    const float* scales = (const float*)d_in[2];   // [11008,32]
    const float* zeros  = (const float*)d_in[3];   // [11008,32]
    const float* iscale = (const float*)d_in[4];   // [4096]
    const float* bias   = (const float*)d_in[5];   // [11008]
    float* out = (float*)d_out;                    // [4,2048,11008] f32

    const int M = in_sizes[0] / IN_F;              // 8192

    // workspace layout: xs (M*IN_F bf16) | wq (OUT_F*IN_F bf16)  => ~157 MB
    bf16_t* xs = (bf16_t*)d_ws;
    bf16_t* wq = (bf16_t*)((char*)d_ws + (size_t)M * IN_F * sizeof(bf16_t));

    // 1) scale + cast x: 33.5M elems / 8 per thread
    scale_cast_kernel<<<(M * IN_F) / 2048, 256, 0, stream>>>(x, iscale, xs);
    // 2) dequant weights: 22.5M int32 / 4 per thread
    dequant_kernel<<<(OUT_F * (IN_F / 2)) / 1024, 256, 0, stream>>>(qw, scales, zeros, wq);
    // 3) GEMM + bias
    gemm_bt_kernel<<<dim3(OUT_F / BN, M / BM), 256, 0, stream>>>(xs, wq, bias, out);
}